// Round 7
// baseline (17494.487 us; speedup 1.0000x reference)
//
#include <hip/hip_runtime.h>
#include <math.h>

#define T_STEPS 4096
#define HID     1024
#define G4      4096   // 4*HID gate rows
#define NB      256    // recurrence blocks (one per CU, all co-resident)
#define TPB     256    // 4 waves per block

// ---- tagged-word publish: one 64-bit atomic = {u32 step-tag | f32 value} ----
__device__ __forceinline__ unsigned long long ld64(const unsigned long long* p) {
    return __hip_atomic_load(p, __ATOMIC_RELAXED, __HIP_MEMORY_SCOPE_AGENT);
}
__device__ __forceinline__ void st64(unsigned long long* p, unsigned long long v) {
    __hip_atomic_store(p, v, __ATOMIC_RELAXED, __HIP_MEMORY_SCOPE_AGENT);
}
__device__ __forceinline__ unsigned long long packhv(float h, unsigned tag) {
    return ((unsigned long long)tag << 32) | (unsigned long long)__float_as_uint(h);
}
__device__ __forceinline__ float fsigmoid(float x) {
    return __fdividef(1.0f, 1.0f + __expf(-x));
}
__device__ __forceinline__ float ftanh(float x) {
    return __fdividef(2.0f, 1.0f + __expf(-2.0f * x)) - 1.0f;
}

// ---------------------------------------------------------------------------
// Kernel 1: xg[t][r] = dot(x[t,:], w_ih[r,:]) + b_ih[r] + b_hh[r]
// f32 GEMM, 64x64 tile, K-chunk 32, 256 threads, 4x4 per thread.
// Blocks (0, y<8) also zero h_pub (2x1024 u64) so each graph replay resets.
// ---------------------------------------------------------------------------
__global__ __launch_bounds__(256) void xg_gemm(
    const float* __restrict__ x, const float* __restrict__ w_ih,
    const float* __restrict__ b_ih, const float* __restrict__ b_hh,
    float* __restrict__ xg, unsigned long long* __restrict__ h_pub)
{
    if (blockIdx.x == 0 && blockIdx.y < 8)
        h_pub[blockIdx.y * 256 + threadIdx.x] = 0ull;

    __shared__ float Xs[32][68];   // [k][m], pad kills conflicts
    __shared__ float Ws[32][68];   // [k][n]

    const int t0  = blockIdx.y * 64;
    const int n0  = blockIdx.x * 64;
    const int thr = threadIdx.x;
    const int tx  = thr & 15;      // n-group
    const int ty  = thr >> 4;      // m-group

    float acc[4][4] = {};

    for (int kk = 0; kk < 1024; kk += 32) {
        #pragma unroll
        for (int i = 0; i < 2; i++) {
            int flat = thr + i * 256;       // 0..511
            int m    = flat >> 3;           // 0..63
            int kc   = flat & 7;            // k-chunk (4 floats)
            float4 xv = *(const float4*)(x    + (size_t)(t0 + m) * 1024 + kk + kc * 4);
            float4 wv = *(const float4*)(w_ih + (size_t)(n0 + m) * 1024 + kk + kc * 4);
            Xs[kc*4+0][m] = xv.x; Xs[kc*4+1][m] = xv.y;
            Xs[kc*4+2][m] = xv.z; Xs[kc*4+3][m] = xv.w;
            Ws[kc*4+0][m] = wv.x; Ws[kc*4+1][m] = wv.y;
            Ws[kc*4+2][m] = wv.z; Ws[kc*4+3][m] = wv.w;
        }
        __syncthreads();
        #pragma unroll
        for (int k = 0; k < 32; k++) {
            float4 a4 = *(const float4*)&Xs[k][ty * 4];
            float4 b4 = *(const float4*)&Ws[k][tx * 4];
            float av[4] = {a4.x, a4.y, a4.z, a4.w};
            float bv[4] = {b4.x, b4.y, b4.z, b4.w};
            #pragma unroll
            for (int i = 0; i < 4; i++)
                #pragma unroll
                for (int j = 0; j < 4; j++)
                    acc[i][j] = fmaf(av[i], bv[j], acc[i][j]);
        }
        __syncthreads();
    }

    float4 bi = *(const float4*)(b_ih + n0 + tx * 4);
    float4 bh = *(const float4*)(b_hh + n0 + tx * 4);
    float bb[4] = {bi.x + bh.x, bi.y + bh.y, bi.z + bh.z, bi.w + bh.w};
    #pragma unroll
    for (int i = 0; i < 4; i++) {
        float4 o;
        o.x = acc[i][0] + bb[0]; o.y = acc[i][1] + bb[1];
        o.z = acc[i][2] + bb[2]; o.w = acc[i][3] + bb[3];
        *(float4*)(xg + (size_t)(t0 + ty * 4 + i) * G4 + n0 + tx * 4) = o;
    }
}

// ---------------------------------------------------------------------------
// Kernel 2: persistent recurrence, full-chip. 256 blocks x 256 threads,
// exactly 1 block/CU (72KB LDS pad forces sole residency).
// Block b owns hidden units [4b, 4b+4). Wave rg (0..3) owns unit 4b+rg:
// 4 gate rows x 1024 elems; lane ec handles elems [16ec, 16ec+16) of all
// 4 rows -> only 64 weight floats/thread (float4 w4[4][4], const-indexed),
// which fits VGPRs under __launch_bounds__(256,1)'s 512-reg cap.
// Per step: prefetch xg -> poll own 4 tagged h words -> float4-stage to
// h_lds[parity] -> barrier -> 4x16 dot -> 7-shuffle fold (lane holds gate
// ec&3) -> +xg -> parallel nonlinearity on all lanes -> 3-shuffle gather ->
// cell update + publish on lane 0. ONE barrier per step, no fences.
// ---------------------------------------------------------------------------
__global__ __launch_bounds__(256, 1) void lstm_rec(
    const float* __restrict__ xg, const float* __restrict__ w_hh,
    const float* __restrict__ h0, const float* __restrict__ c0,
    const float* __restrict__ w_out, const float* __restrict__ b_out,
    unsigned long long* __restrict__ h_pub,   // [2][HID] tagged words
    float* __restrict__ out)
{
    __shared__ float h_lds[2][64 * 20];   // double-buffered, stride-20 chunks
    __shared__ float red_lds[4];
    __shared__ float lds_pad[18432];      // 72KB: force 1 block/CU

    const int thr = threadIdx.x;
    const int b   = blockIdx.x;
    const int rg  = thr >> 6;          // wave 0..3
    const int ec  = thr & 63;          // lane 0..63

    if (thr == 0) ((volatile float*)lds_pad)[0] = 0.0f;   // keep pad alive

    const int unit = 4 * b + rg;       // this wave's hidden unit

    // ---- preload weights: w4[rr][q] = w_hh[rr*HID + unit][16ec + 4q .. +3]
    float4 w4[4][4];
    #pragma unroll
    for (int rr = 0; rr < 4; rr++) {
        const float* wr = w_hh + (size_t)(rr * HID + unit) * HID + ec * 16;
        #pragma unroll
        for (int q = 0; q < 4; q++)
            w4[rr][q] = *(const float4*)(wr + q * 4);
    }

    // ---- init: c lives on lane 0 of each wave
    float c = 0.0f;
    if (ec == 0) {
        c = c0[unit];
        st64(&h_pub[0 * HID + unit], packhv(h0[unit], 1u));
    }

    const int u0 = 4 * thr;            // this thread's four staged h units
    const int l0 = (u0 >> 4) * 20 + (u0 & 15);
    const int xrow = (ec & 3) * HID + unit;   // xg row this lane will hold

    for (int t = 0; t < T_STEPS; t++) {
        const int p = t & 1;

        // xg prefetch (independent of the handoff)
        float xgv = xg[(size_t)t * G4 + xrow];

        // ---- spin on own four tagged words
        const unsigned tag = (unsigned)(t + 1);
        const unsigned long long* a0 = &h_pub[p * HID + u0];
        unsigned long long v0 = ld64(a0),     v1 = ld64(a0 + 1),
                           v2 = ld64(a0 + 2), v3 = ld64(a0 + 3);
        while (((unsigned)(v0 >> 32) != tag) | ((unsigned)(v1 >> 32) != tag) |
               ((unsigned)(v2 >> 32) != tag) | ((unsigned)(v3 >> 32) != tag)) {
            v0 = ld64(a0);     v1 = ld64(a0 + 1);
            v2 = ld64(a0 + 2); v3 = ld64(a0 + 3);
        }
        float4 hw;
        hw.x = __uint_as_float((unsigned)v0);
        hw.y = __uint_as_float((unsigned)v1);
        hw.z = __uint_as_float((unsigned)v2);
        hw.w = __uint_as_float((unsigned)v3);
        *(float4*)&h_lds[p][l0] = hw;
        __syncthreads();

        // ---- dot: 4 rows x 16 elems per thread
        float4 h4[4];
        #pragma unroll
        for (int q = 0; q < 4; q++)
            h4[q] = *(const float4*)&h_lds[p][ec * 20 + q * 4];

        float a[4];
        #pragma unroll
        for (int rr = 0; rr < 4; rr++) {
            float s0 = 0.f, s1 = 0.f, s2 = 0.f, s3 = 0.f;
            #pragma unroll
            for (int q = 0; q < 4; q++) {
                s0 = fmaf(w4[rr][q].x, h4[q].x, s0);
                s1 = fmaf(w4[rr][q].y, h4[q].y, s1);
                s2 = fmaf(w4[rr][q].z, h4[q].z, s2);
                s3 = fmaf(w4[rr][q].w, h4[q].w, s3);
            }
            a[rr] = (s0 + s1) + (s2 + s3);
        }

        // ---- fold: 4 accs x 64 lanes -> lane ec holds gate (ec&3)
        const bool b0 = (ec & 1), b1 = (ec & 2);
        float f[2];
        #pragma unroll
        for (int i = 0; i < 2; i++) {
            float send = b0 ? a[2*i] : a[2*i+1];
            float recv = __shfl_xor(send, 1, 64);
            f[i] = (b0 ? a[2*i+1] : a[2*i]) + recv;
        }
        float d;
        {
            float send = b1 ? f[0] : f[1];
            float recv = __shfl_xor(send, 2, 64);
            d = (b1 ? f[1] : f[0]) + recv;
        }
        d += __shfl_xor(d, 4, 64);
        d += __shfl_xor(d, 8, 64);
        d += __shfl_xor(d, 16, 64);
        d += __shfl_xor(d, 32, 64);
        d += xgv;                       // full preact for gate (ec&3)

        // ---- parallel nonlinearity: gate g on lanes with (ec&3)==g
        float nl = ((ec & 3) == 2) ? ftanh(d) : fsigmoid(d);
        float sf = __shfl_xor(nl, 1, 64);   // gate f (lane^1)
        float tg = __shfl_xor(nl, 2, 64);   // gate g (lane^2)
        float so = __shfl_xor(nl, 3, 64);   // gate o (lane^3)

        if (ec == 0) {
            c = sf * c + nl * tg;           // nl == sigmoid(i) on lane 0
            float hn = so * ftanh(c);
            st64(&h_pub[(p ^ 1) * HID + unit], packhv(hn, (unsigned)(t + 2)));
        }
    }

    // ---- tail: block 0 computes pred = tanh(w_out . h_final + b_out)
    if (b == 0) {
        const unsigned tag = (unsigned)(T_STEPS + 1);    // final h in buffer 0
        const unsigned long long* a0 = &h_pub[0 * HID + u0];
        unsigned long long v0 = ld64(a0),     v1 = ld64(a0 + 1),
                           v2 = ld64(a0 + 2), v3 = ld64(a0 + 3);
        while (((unsigned)(v0 >> 32) != tag) | ((unsigned)(v1 >> 32) != tag) |
               ((unsigned)(v2 >> 32) != tag) | ((unsigned)(v3 >> 32) != tag)) {
            v0 = ld64(a0);     v1 = ld64(a0 + 1);
            v2 = ld64(a0 + 2); v3 = ld64(a0 + 3);
        }
        float part = __uint_as_float((unsigned)v0) * w_out[u0]
                   + __uint_as_float((unsigned)v1) * w_out[u0 + 1]
                   + __uint_as_float((unsigned)v2) * w_out[u0 + 2]
                   + __uint_as_float((unsigned)v3) * w_out[u0 + 3];
        #pragma unroll
        for (int m = 1; m < 64; m <<= 1)
            part += __shfl_xor(part, m, 64);
        __syncthreads();
        if (ec == 0) red_lds[rg] = part;
        __syncthreads();
        if (thr == 0) {
            float s = red_lds[0] + red_lds[1] + red_lds[2] + red_lds[3];
            out[0] = tanhf(s + b_out[0]);
        }
    }
}

// ---------------------------------------------------------------------------
extern "C" void kernel_launch(void* const* d_in, const int* in_sizes, int n_in,
                              void* d_out, int out_size, void* d_ws, size_t ws_size,
                              hipStream_t stream) {
    const float* x     = (const float*)d_in[0];
    const float* h0    = (const float*)d_in[1];
    const float* c0    = (const float*)d_in[2];
    const float* w_ih  = (const float*)d_in[3];
    const float* w_hh  = (const float*)d_in[4];
    const float* b_ih  = (const float*)d_in[5];
    const float* b_hh  = (const float*)d_in[6];
    const float* w_out = (const float*)d_in[7];
    const float* b_out = (const float*)d_in[8];
    float* out = (float*)d_out;

    char* ws = (char*)d_ws;
    float*              xg    = (float*)ws;                               // 64 MiB
    unsigned long long* h_pub = (unsigned long long*)(ws + (size_t)T_STEPS * G4 * 4);  // 16 KiB

    xg_gemm<<<dim3(64, 64), 256, 0, stream>>>(x, w_ih, b_ih, b_hh, xg, h_pub);
    lstm_rec<<<NB, TPB, 0, stream>>>(xg, w_hh, h0, c0, w_out, b_out, h_pub, out);
}

// Round 8
// 15673.782 us; speedup vs baseline: 1.1162x; 1.1162x over previous
//
#include <hip/hip_runtime.h>
#include <math.h>

#define T_STEPS 4096
#define HID     1024
#define G4      4096   // 4*HID gate rows
#define NB      64     // recurrence blocks
#define TPB     1024   // 16 waves per block

// ---- tagged-word publish: one 64-bit atomic = {u32 step-tag | f32 value} ----
__device__ __forceinline__ unsigned long long ld64(const unsigned long long* p) {
    return __hip_atomic_load(p, __ATOMIC_RELAXED, __HIP_MEMORY_SCOPE_AGENT);
}
__device__ __forceinline__ void st64(unsigned long long* p, unsigned long long v) {
    __hip_atomic_store(p, v, __ATOMIC_RELAXED, __HIP_MEMORY_SCOPE_AGENT);
}
__device__ __forceinline__ unsigned long long packhv(float h, unsigned tag) {
    return ((unsigned long long)tag << 32) | (unsigned long long)__float_as_uint(h);
}
__device__ __forceinline__ float fsigmoid(float x) {
    return __fdividef(1.0f, 1.0f + __expf(-x));
}
__device__ __forceinline__ float ftanh(float x) {
    return __fdividef(2.0f, 1.0f + __expf(-2.0f * x)) - 1.0f;
}

// ---------------------------------------------------------------------------
// Kernel 1: xg[t][r] = dot(x[t,:], w_ih[r,:]) + b_ih[r] + b_hh[r]
// f32 GEMM, 64x64 tile, K-chunk 32, 256 threads, 4x4 per thread.
// Blocks (0, y<8) also zero h_pub (2x1024 u64) so each graph replay resets.
// ---------------------------------------------------------------------------
__global__ __launch_bounds__(256) void xg_gemm(
    const float* __restrict__ x, const float* __restrict__ w_ih,
    const float* __restrict__ b_ih, const float* __restrict__ b_hh,
    float* __restrict__ xg, unsigned long long* __restrict__ h_pub)
{
    if (blockIdx.x == 0 && blockIdx.y < 8)
        h_pub[blockIdx.y * 256 + threadIdx.x] = 0ull;

    __shared__ float Xs[32][68];   // [k][m], pad kills conflicts
    __shared__ float Ws[32][68];   // [k][n]

    const int t0  = blockIdx.y * 64;
    const int n0  = blockIdx.x * 64;
    const int thr = threadIdx.x;
    const int tx  = thr & 15;      // n-group
    const int ty  = thr >> 4;      // m-group

    float acc[4][4] = {};

    for (int kk = 0; kk < 1024; kk += 32) {
        #pragma unroll
        for (int i = 0; i < 2; i++) {
            int flat = thr + i * 256;       // 0..511
            int m    = flat >> 3;           // 0..63
            int kc   = flat & 7;            // k-chunk (4 floats)
            float4 xv = *(const float4*)(x    + (size_t)(t0 + m) * 1024 + kk + kc * 4);
            float4 wv = *(const float4*)(w_ih + (size_t)(n0 + m) * 1024 + kk + kc * 4);
            Xs[kc*4+0][m] = xv.x; Xs[kc*4+1][m] = xv.y;
            Xs[kc*4+2][m] = xv.z; Xs[kc*4+3][m] = xv.w;
            Ws[kc*4+0][m] = wv.x; Ws[kc*4+1][m] = wv.y;
            Ws[kc*4+2][m] = wv.z; Ws[kc*4+3][m] = wv.w;
        }
        __syncthreads();
        #pragma unroll
        for (int k = 0; k < 32; k++) {
            float4 a4 = *(const float4*)&Xs[k][ty * 4];
            float4 b4 = *(const float4*)&Ws[k][tx * 4];
            float av[4] = {a4.x, a4.y, a4.z, a4.w};
            float bv[4] = {b4.x, b4.y, b4.z, b4.w};
            #pragma unroll
            for (int i = 0; i < 4; i++)
                #pragma unroll
                for (int j = 0; j < 4; j++)
                    acc[i][j] = fmaf(av[i], bv[j], acc[i][j]);
        }
        __syncthreads();
    }

    float4 bi = *(const float4*)(b_ih + n0 + tx * 4);
    float4 bh = *(const float4*)(b_hh + n0 + tx * 4);
    float bb[4] = {bi.x + bh.x, bi.y + bh.y, bi.z + bh.z, bi.w + bh.w};
    #pragma unroll
    for (int i = 0; i < 4; i++) {
        float4 o;
        o.x = acc[i][0] + bb[0]; o.y = acc[i][1] + bb[1];
        o.z = acc[i][2] + bb[2]; o.w = acc[i][3] + bb[3];
        *(float4*)(xg + (size_t)(t0 + ty * 4 + i) * G4 + n0 + tx * 4) = o;
    }
}

// ---------------------------------------------------------------------------
// Kernel 2: persistent recurrence. 64 blocks x 1024 threads (16 waves),
// __launch_bounds__(1024,4) -> 128-VGPR cap, 1 block/CU.
// Block b owns hidden units [16b, 16b+16). Wave rg (0..15) owns unit
// 16b+rg: 4 gate rows x 1024 cols; lane ec handles cols [16ec,16ec+16)
// of all 4 rows -> 64 weight floats/thread (float4 w4[4][4], const-indexed;
// proven-resident shape from round 7).
// Per step: prefetch xg -> each thread polls ONE tagged h word (thread thr
// owns unit thr) -> stage to h_lds[parity] -> barrier -> 4x16 dot ->
// 7-shuffle fold (lane holds gate ec&3) -> +xg -> parallel nonlinearity ->
// 3-shuffle gather -> cell update + publish on lane 0 of each wave.
// ONE barrier per step, no fences, 64 participants only.
// ---------------------------------------------------------------------------
__global__ __launch_bounds__(1024, 4) void lstm_rec(
    const float* __restrict__ xg, const float* __restrict__ w_hh,
    const float* __restrict__ h0, const float* __restrict__ c0,
    const float* __restrict__ w_out, const float* __restrict__ b_out,
    unsigned long long* __restrict__ h_pub,   // [2][HID] tagged words
    float* __restrict__ out)
{
    __shared__ float h_lds[2][64 * 20];   // double-buffered, stride-20 chunks
    __shared__ float red_lds[16];

    const int thr = threadIdx.x;       // 0..1023
    const int b   = blockIdx.x;        // 0..63
    const int rg  = thr >> 6;          // wave 0..15
    const int ec  = thr & 63;          // lane 0..63

    const int unit = 16 * b + rg;      // this wave's hidden unit

    // ---- preload weights: w4[rr][q] = w_hh[rr*HID + unit][16ec + 4q .. +3]
    float4 w4[4][4];
    #pragma unroll
    for (int rr = 0; rr < 4; rr++) {
        const float* wr = w_hh + (size_t)(rr * HID + unit) * HID + ec * 16;
        #pragma unroll
        for (int q = 0; q < 4; q++)
            w4[rr][q] = *(const float4*)(wr + q * 4);
    }

    // ---- init: c lives on lane 0 of each wave
    float c = 0.0f;
    if (ec == 0) {
        c = c0[unit];
        st64(&h_pub[0 * HID + unit], packhv(h0[unit], 1u));
    }

    const int l0   = (thr >> 4) * 20 + (thr & 15);   // LDS slot for unit thr
    const int xrow = (ec & 3) * HID + unit;          // xg row this lane holds

    for (int t = 0; t < T_STEPS; t++) {
        const int p = t & 1;

        // xg prefetch (independent of the handoff)
        float xgv = xg[(size_t)t * G4 + xrow];

        // ---- poll own single tagged word (thread thr <-> unit thr)
        const unsigned tag = (unsigned)(t + 1);
        const unsigned long long* a0 = &h_pub[p * HID + thr];
        unsigned long long v0 = ld64(a0);
        while ((unsigned)(v0 >> 32) != tag) v0 = ld64(a0);
        h_lds[p][l0] = __uint_as_float((unsigned)v0);
        __syncthreads();

        // ---- dot: 4 rows x 16 elems per thread
        float4 h4[4];
        #pragma unroll
        for (int q = 0; q < 4; q++)
            h4[q] = *(const float4*)&h_lds[p][ec * 20 + q * 4];

        float a[4];
        #pragma unroll
        for (int rr = 0; rr < 4; rr++) {
            float s0 = 0.f, s1 = 0.f, s2 = 0.f, s3 = 0.f;
            #pragma unroll
            for (int q = 0; q < 4; q++) {
                s0 = fmaf(w4[rr][q].x, h4[q].x, s0);
                s1 = fmaf(w4[rr][q].y, h4[q].y, s1);
                s2 = fmaf(w4[rr][q].z, h4[q].z, s2);
                s3 = fmaf(w4[rr][q].w, h4[q].w, s3);
            }
            a[rr] = (s0 + s1) + (s2 + s3);
        }

        // ---- fold: 4 accs x 64 lanes -> lane ec holds gate (ec&3)
        const bool b0 = (ec & 1), b1 = (ec & 2);
        float f[2];
        #pragma unroll
        for (int i = 0; i < 2; i++) {
            float send = b0 ? a[2*i] : a[2*i+1];
            float recv = __shfl_xor(send, 1, 64);
            f[i] = (b0 ? a[2*i+1] : a[2*i]) + recv;
        }
        float d;
        {
            float send = b1 ? f[0] : f[1];
            float recv = __shfl_xor(send, 2, 64);
            d = (b1 ? f[1] : f[0]) + recv;
        }
        d += __shfl_xor(d, 4, 64);
        d += __shfl_xor(d, 8, 64);
        d += __shfl_xor(d, 16, 64);
        d += __shfl_xor(d, 32, 64);
        d += xgv;                       // full preact for gate (ec&3)

        // ---- parallel nonlinearity: gate g on lanes with (ec&3)==g
        float nl = ((ec & 3) == 2) ? ftanh(d) : fsigmoid(d);
        float sf = __shfl_xor(nl, 1, 64);   // gate f
        float tg = __shfl_xor(nl, 2, 64);   // gate g
        float so = __shfl_xor(nl, 3, 64);   // gate o

        if (ec == 0) {
            c = sf * c + nl * tg;           // nl == sigmoid(i) on lane 0
            float hn = so * ftanh(c);
            st64(&h_pub[(p ^ 1) * HID + unit], packhv(hn, (unsigned)(t + 2)));
        }
    }

    // ---- tail: block 0 computes pred = tanh(w_out . h_final + b_out)
    if (b == 0) {
        const unsigned tag = (unsigned)(T_STEPS + 1);    // final h in buffer 0
        const unsigned long long* a0 = &h_pub[0 * HID + thr];
        unsigned long long v0 = ld64(a0);
        while ((unsigned)(v0 >> 32) != tag) v0 = ld64(a0);
        float part = __uint_as_float((unsigned)v0) * w_out[thr];
        #pragma unroll
        for (int m = 1; m < 64; m <<= 1)
            part += __shfl_xor(part, m, 64);
        __syncthreads();
        if (ec == 0) red_lds[rg] = part;
        __syncthreads();
        if (thr == 0) {
            float s = 0.f;
            #pragma unroll
            for (int i = 0; i < 16; i++) s += red_lds[i];
            out[0] = tanhf(s + b_out[0]);
        }
    }
}

// ---------------------------------------------------------------------------
extern "C" void kernel_launch(void* const* d_in, const int* in_sizes, int n_in,
                              void* d_out, int out_size, void* d_ws, size_t ws_size,
                              hipStream_t stream) {
    const float* x     = (const float*)d_in[0];
    const float* h0    = (const float*)d_in[1];
    const float* c0    = (const float*)d_in[2];
    const float* w_ih  = (const float*)d_in[3];
    const float* w_hh  = (const float*)d_in[4];
    const float* b_ih  = (const float*)d_in[5];
    const float* b_hh  = (const float*)d_in[6];
    const float* w_out = (const float*)d_in[7];
    const float* b_out = (const float*)d_in[8];
    float* out = (float*)d_out;

    char* ws = (char*)d_ws;
    float*              xg    = (float*)ws;                               // 64 MiB
    unsigned long long* h_pub = (unsigned long long*)(ws + (size_t)T_STEPS * G4 * 4);  // 16 KiB

    xg_gemm<<<dim3(64, 64), 256, 0, stream>>>(x, w_ih, b_ih, b_hh, xg, h_pub);
    lstm_rec<<<NB, TPB, 0, stream>>>(xg, w_hh, h0, c0, w_out, b_out, h_pub, out);
}